// Round 2
// baseline (1009.170 us; speedup 1.0000x reference)
//
#include <hip/hip_runtime.h>
#include <hip/hip_bf16.h>
#include <cstdint>
#include <cstddef>

// Problem constants (fixed by the reference): B=64, H=1024, V=32000, DEPTH=5
// ALL harness tensors are fp32 (threshold analysis: 2%-relative, no bf16 floor).
// Internal compute: bf16 MFMA, fp32 accumulate/epilogue.
#define H_DIM   1024
#define B_DIM   64
#define V_DIM   32000
#define DEPTH_C 5

using bf16x8  = __attribute__((ext_vector_type(8))) __bf16;
using floatx4 = __attribute__((ext_vector_type(4))) float;

// fp32 -> bf16 elementwise convert (for encoding only; weights converted inline)
__global__ __launch_bounds__(256) void f2b_kernel(const float* __restrict__ in,
                                                  __bf16* __restrict__ out, int n) {
  int i = (blockIdx.x * 256 + threadIdx.x) * 4;
  if (i < n) {
    float4 v = *(const float4*)(in + i);
    out[i + 0] = (__bf16)v.x;
    out[i + 1] = (__bf16)v.y;
    out[i + 2] = (__bf16)v.z;
    out[i + 3] = (__bf16)v.w;
  }
}

__device__ inline bf16x8 cvt8(float4 a, float4 b) {
  bf16x8 r;
  r[0] = (__bf16)a.x; r[1] = (__bf16)a.y; r[2] = (__bf16)a.z; r[3] = (__bf16)a.w;
  r[4] = (__bf16)b.x; r[5] = (__bf16)b.y; r[6] = (__bf16)b.z; r[7] = (__bf16)b.w;
  return r;
}

// ---------------------------------------------------------------------------
// NT GEMM: C[M,N] = A[M,K] * W[N,K]^T, K = 1024. A is bf16; W is fp32,
// converted to bf16 inline while staging to LDS. C is fp32.
// 128x128 tile, 256 threads = 4 waves (2x2), each wave 64x64 via 4x4 grid of
// 16x16x32 bf16 MFMA.
// LOGITS=true : C += bias (final projection)
// LOGITS=false: W = (n<3072 ? W0 : W1)  (fused left|right GRU gh)
// ---------------------------------------------------------------------------
template <bool LOGITS>
__global__ __launch_bounds__(256) void gemm_nt(
    const __bf16* __restrict__ A, const float* __restrict__ W0,
    const float* __restrict__ W1, float* __restrict__ C,
    const float* __restrict__ bias, int M, int N) {
  constexpr int K = H_DIM;
  __shared__ __align__(16) __bf16 As[128 * 32];
  __shared__ __align__(16) __bf16 Bs[128 * 32];

  const int tid  = threadIdx.x;
  const int m0   = blockIdx.y * 128;
  const int n0   = blockIdx.x * 128;
  const int lane = tid & 63;
  const int wave = tid >> 6;
  const int wm   = (wave >> 1) * 64;
  const int wn   = (wave & 1) * 64;
  const int lrow = lane & 15;
  const int quad = lane >> 4;

  const float* W = W0;
  int nw0 = n0;
  if (!LOGITS && n0 >= 3072) { W = W1; nw0 = n0 - 3072; }

  floatx4 acc[4][4] = {};

  // staging: each thread covers rows sr and sr+64, 8 elements starting at sk
  const int sr = tid >> 2;       // 0..63
  const int sk = (tid & 3) * 8;  // 0,8,16,24

  int ra0 = m0 + sr;      if (ra0 >= M) ra0 = M - 1;  // clamp for M=64 depth
  int ra1 = m0 + sr + 64; if (ra1 >= M) ra1 = M - 1;
  const float* wr0 = W + (size_t)(nw0 + sr) * K + sk;
  const float* wr1 = W + (size_t)(nw0 + sr + 64) * K + sk;

  for (int kt = 0; kt < K; kt += 32) {
    bf16x8 a0 = *(const bf16x8*)(A + (size_t)ra0 * K + kt + sk);
    bf16x8 a1 = *(const bf16x8*)(A + (size_t)ra1 * K + kt + sk);
    float4 w00 = *(const float4*)(wr0 + kt);
    float4 w01 = *(const float4*)(wr0 + kt + 4);
    float4 w10 = *(const float4*)(wr1 + kt);
    float4 w11 = *(const float4*)(wr1 + kt + 4);
    __syncthreads();  // previous iteration's LDS reads complete
    *(bf16x8*)(&As[sr * 32 + sk])        = a0;
    *(bf16x8*)(&As[(sr + 64) * 32 + sk]) = a1;
    *(bf16x8*)(&Bs[sr * 32 + sk])        = cvt8(w00, w01);
    *(bf16x8*)(&Bs[(sr + 64) * 32 + sk]) = cvt8(w10, w11);
    __syncthreads();

    bf16x8 af[4], bfr[4];
#pragma unroll
    for (int i = 0; i < 4; i++)
      af[i] = *(const bf16x8*)(&As[(wm + i * 16 + lrow) * 32 + quad * 8]);
#pragma unroll
    for (int j = 0; j < 4; j++)
      bfr[j] = *(const bf16x8*)(&Bs[(wn + j * 16 + lrow) * 32 + quad * 8]);
#pragma unroll
    for (int i = 0; i < 4; i++)
#pragma unroll
      for (int j = 0; j < 4; j++)
        acc[i][j] =
            __builtin_amdgcn_mfma_f32_16x16x32_bf16(af[i], bfr[j], acc[i][j], 0, 0, 0);
  }

  // epilogue. C/D layout: col = lane&15, row = quad*4 + reg  [m89-verified]
#pragma unroll
  for (int i = 0; i < 4; i++) {
#pragma unroll
    for (int j = 0; j < 4; j++) {
      const int col = n0 + wn + j * 16 + lrow;
      const float bv = LOGITS ? bias[col] : 0.0f;
#pragma unroll
      for (int r = 0; r < 4; r++) {
        const int row = m0 + wm + i * 16 + quad * 4 + r;
        if (row < M) C[(size_t)row * N + col] = acc[i][j][r] + bv;
      }
    }
  }
}

// ---------------------------------------------------------------------------
// GRU gates. gh (M x 6144 fp32) = [left 3H | right 3H] WITHOUT biases.
// r = sig(bih_r + gh_r + bhh_r); z likewise; n = tanh(bih_n + r*(gh_n + bhh_n))
// children interleaved: left -> 2j, right -> 2j+1.  grid = (M, 4), block 256.
// ---------------------------------------------------------------------------
__global__ __launch_bounds__(256) void gru_gate(
    const float* __restrict__ gh, const float* __restrict__ bih_l,
    const float* __restrict__ bhh_l, const float* __restrict__ bih_r,
    const float* __restrict__ bhh_r, const __bf16* __restrict__ hin,
    __bf16* __restrict__ hout, int n) {
  const int row = blockIdx.x;
  const int col = blockIdx.y * 256 + threadIdx.x;
  const int b = row / n, j = row - b * n;
  const size_t g6 = (size_t)row * 6144;
  const float hv = (float)hin[(size_t)row * H_DIM + col];
  const size_t obase = (size_t)(b * 2 * n + 2 * j) * H_DIM;

  {  // left child
    float gr = gh[g6 + col] + bhh_l[col];
    float gz = gh[g6 + 1024 + col] + bhh_l[1024 + col];
    float gn = gh[g6 + 2048 + col] + bhh_l[2048 + col];
    float r = 1.f / (1.f + __expf(-(bih_l[col] + gr)));
    float z = 1.f / (1.f + __expf(-(bih_l[1024 + col] + gz)));
    float nn = tanhf(bih_l[2048 + col] + r * gn);
    hout[obase + col] = (__bf16)((1.f - z) * nn + z * hv);
  }
  {  // right child
    float gr = gh[g6 + 3072 + col] + bhh_r[col];
    float gz = gh[g6 + 4096 + col] + bhh_r[1024 + col];
    float gn = gh[g6 + 5120 + col] + bhh_r[2048 + col];
    float r = 1.f / (1.f + __expf(-(bih_r[col] + gr)));
    float z = 1.f / (1.f + __expf(-(bih_r[1024 + col] + gz)));
    float nn = tanhf(bih_r[2048 + col] + r * gn);
    hout[obase + H_DIM + col] = (__bf16)((1.f - z) * nn + z * hv);
  }
}

// ---------------------------------------------------------------------------
// Row-wise log_softmax over V=32000, in place on fp32 logits.
// One block (256 thr) per row: max -> sum(exp) -> rewrite.
// ---------------------------------------------------------------------------
__global__ __launch_bounds__(256) void logsoftmax_rows(float* __restrict__ out) {
  const int row = blockIdx.x;
  float* p = out + (size_t)row * V_DIM;
  const int tid = threadIdx.x;
  __shared__ float red[4], red2[4];

  float m = -3.0e38f;
  for (int i = tid; i < V_DIM; i += 256) m = fmaxf(m, p[i]);
#pragma unroll
  for (int off = 32; off; off >>= 1) m = fmaxf(m, __shfl_xor(m, off, 64));
  if ((tid & 63) == 0) red[tid >> 6] = m;
  __syncthreads();
  m = fmaxf(fmaxf(red[0], red[1]), fmaxf(red[2], red[3]));

  float s = 0.f;
  for (int i = tid; i < V_DIM; i += 256) s += __expf(p[i] - m);
#pragma unroll
  for (int off = 32; off; off >>= 1) s += __shfl_xor(s, off, 64);
  if ((tid & 63) == 0) red2[tid >> 6] = s;
  __syncthreads();
  s = red2[0] + red2[1] + red2[2] + red2[3];

  const float lg = m + __logf(s);
  for (int i = tid; i < V_DIM; i += 256) p[i] = p[i] - lg;
}

// ---------------------------------------------------------------------------
extern "C" void kernel_launch(void* const* d_in, const int* in_sizes, int n_in,
                              void* d_out, int out_size, void* d_ws,
                              size_t ws_size, hipStream_t stream) {
  const float* enc   = (const float*)d_in[0];
  const float* Whh_l = (const float*)d_in[1];
  const float* bih_l = (const float*)d_in[2];
  const float* bhh_l = (const float*)d_in[3];
  const float* Whh_r = (const float*)d_in[4];
  const float* bih_r = (const float*)d_in[5];
  const float* bhh_r = (const float*)d_in[6];
  const float* W_out = (const float*)d_in[7];
  const float* b_out = (const float*)d_in[8];
  float* out = (float*)d_out;

  // ws layout: buf0 (4MB) | buf1 (4MB) | gh (1024*6144 fp32 = 24MB) | encB
  char* ws = (char*)d_ws;
  __bf16* buf0 = (__bf16*)ws;
  __bf16* buf1 = (__bf16*)(ws + ((size_t)4 << 20));
  float*  gh   = (float*)(ws + ((size_t)8 << 20));
  __bf16* encB = (__bf16*)(ws + ((size_t)32 << 20));

  // encoding fp32 -> bf16 (65536 elements)
  f2b_kernel<<<B_DIM * H_DIM / 1024, 256, 0, stream>>>(enc, encB, B_DIM * H_DIM);

  const __bf16* cur = encB;
  __bf16* nxt = buf0;
  int n = 1;
  for (int d = 0; d < DEPTH_C; d++) {
    const int M = B_DIM * n;
    dim3 gg(6144 / 128, (M + 127) / 128);
    gemm_nt<false><<<gg, 256, 0, stream>>>(cur, Whh_l, Whh_r, gh, nullptr, M,
                                           6144);
    gru_gate<<<dim3(M, 4), 256, 0, stream>>>(gh, bih_l, bhh_l, bih_r, bhh_r,
                                             cur, nxt, n);
    cur = nxt;
    nxt = (nxt == buf0) ? buf1 : buf0;
    n *= 2;
  }

  // cur: 2048 x 1024 bf16 leaves. logits = cur @ W_out^T + b_out -> d_out fp32
  dim3 gf(V_DIM / 128, 2048 / 128);
  gemm_nt<true><<<gf, 256, 0, stream>>>(cur, W_out, nullptr, out, b_out, 2048,
                                        V_DIM);
  logsoftmax_rows<<<2048, 256, 0, stream>>>(out);
}

// Round 3
// 824.415 us; speedup vs baseline: 1.2241x; 1.2241x over previous
//
#include <hip/hip_runtime.h>
#include <hip/hip_bf16.h>
#include <cstdint>
#include <cstddef>

// B=64, H=1024, V=32000, DEPTH=5. Harness tensors are fp32; internal compute
// bf16 MFMA + fp32 accumulate. Weights pre-converted to bf16 in ws.
#define H_DIM   1024
#define B_DIM   64
#define V_DIM   32000
#define DEPTH_C 5

using bf16x8  = __attribute__((ext_vector_type(8))) __bf16;
using bf16x4  = __attribute__((ext_vector_type(4))) __bf16;
using floatx4 = __attribute__((ext_vector_type(4))) float;

// async global->LDS, 16B per lane. LDS dest must be wave-uniform base + lane*16
// (our tid*16 mapping satisfies this per-wave by construction).
__device__ __forceinline__ void gl_lds16(const __bf16* g, __bf16* l) {
  __builtin_amdgcn_global_load_lds(
      (const __attribute__((address_space(1))) unsigned int*)g,
      (__attribute__((address_space(3))) unsigned int*)l, 16, 0, 0);
}

// grid-stride fp32 -> bf16 (n % 4 == 0)
__global__ __launch_bounds__(256) void f2b(const float* __restrict__ in,
                                           __bf16* __restrict__ out, int n) {
  for (int i = (blockIdx.x * 256 + threadIdx.x) * 4; i < n;
       i += gridDim.x * 1024) {
    float4 v = *(const float4*)(in + i);
    bf16x4 o;
    o[0] = (__bf16)v.x; o[1] = (__bf16)v.y; o[2] = (__bf16)v.z; o[3] = (__bf16)v.w;
    *(bf16x4*)(out + i) = o;
  }
}

__device__ __forceinline__ bf16x8 cvt8(float4 a, float4 b) {
  bf16x8 r;
  r[0] = (__bf16)a.x; r[1] = (__bf16)a.y; r[2] = (__bf16)a.z; r[3] = (__bf16)a.w;
  r[4] = (__bf16)b.x; r[5] = (__bf16)b.y; r[6] = (__bf16)b.z; r[7] = (__bf16)b.w;
  return r;
}

// ---------------------------------------------------------------------------
// NT GEMM: C[M,N] = A[M,K] * W[N,K]^T, K=1024, A bf16.
// Block tile 128 x TN, 256 threads. TN=128: 4 waves 2x2 (wave 64x64, acc 4x4).
// TN=64: 4 waves stacked in M (wave 32x64, acc 2x4).
// blockIdx.x = M-tile (fastest) so consecutive blocks share the W strip.
// WBF16: W already bf16 -> global_load_lds staging. else fp32 W inline-cvt.
// LOGITS: C fp32 += bias. else C bf16 (gh), W split left|right at n=3072.
// ---------------------------------------------------------------------------
template <int TN, bool LOGITS, bool WBF16>
__global__ __launch_bounds__(256) void gemm_nt(
    const __bf16* __restrict__ A, const __bf16* __restrict__ Wb0,
    const __bf16* __restrict__ Wb1, const float* __restrict__ Wf,
    __bf16* __restrict__ Cb, float* __restrict__ Cf,
    const float* __restrict__ bias, int M, int N) {
  constexpr int K = H_DIM;
  constexpr int MI = (TN == 128) ? 4 : 2;
  __shared__ __align__(16) __bf16 As[128 * 32];
  __shared__ __align__(16) __bf16 Bs[TN * 32];

  const int tid  = threadIdx.x;
  const int m0   = blockIdx.x * 128;
  const int n0   = blockIdx.y * TN;
  const int lane = tid & 63;
  const int wave = tid >> 6;
  const int lrow = lane & 15;
  const int quad = lane >> 4;
  const int wm   = (TN == 128) ? (wave >> 1) * 64 : wave * 32;
  const int wn   = (TN == 128) ? (wave & 1) * 64 : 0;

  const __bf16* Wb = Wb0;
  int nw0 = n0;
  if (!LOGITS && n0 >= 3072) { Wb = Wb1; nw0 = n0 - 3072; }

  const int sr = tid >> 2;       // 0..63
  const int sk = (tid & 3) * 8;  // 0,8,16,24

  int ra0 = m0 + sr;      if (ra0 >= M) ra0 = M - 1;  // clamp (M=64 depth 0)
  int ra1 = m0 + sr + 64; if (ra1 >= M) ra1 = M - 1;
  const __bf16* ga0 = A + (size_t)ra0 * K + sk;
  const __bf16* ga1 = A + (size_t)ra1 * K + sk;
  const __bf16* gb0 = nullptr; const __bf16* gb1 = nullptr;
  const float* gf0 = nullptr; const float* gf1 = nullptr;
  if (WBF16) {
    gb0 = Wb + (size_t)(nw0 + sr) * K + sk;
    if (TN == 128) gb1 = Wb + (size_t)(nw0 + sr + 64) * K + sk;
  } else {
    gf0 = Wf + (size_t)(n0 + sr) * K + sk;
    gf1 = Wf + (size_t)(n0 + sr + 64) * K + sk;
  }

  floatx4 acc[MI][4] = {};

  for (int kt = 0; kt < K; kt += 32) {
    float4 w00, w01, w10, w11;
    if (!WBF16) {
      w00 = *(const float4*)(gf0 + kt);
      w01 = *(const float4*)(gf0 + kt + 4);
      w10 = *(const float4*)(gf1 + kt);
      w11 = *(const float4*)(gf1 + kt + 4);
    }
    __syncthreads();  // prior tile's LDS reads complete
    gl_lds16(ga0 + kt, As + tid * 8);
    gl_lds16(ga1 + kt, As + 2048 + tid * 8);
    if (WBF16) {
      gl_lds16(gb0 + kt, Bs + tid * 8);
      if (TN == 128) gl_lds16(gb1 + kt, Bs + 2048 + tid * 8);
    } else {
      *(bf16x8*)(&Bs[sr * 32 + sk])        = cvt8(w00, w01);
      *(bf16x8*)(&Bs[(sr + 64) * 32 + sk]) = cvt8(w10, w11);
    }
    __syncthreads();  // vmcnt(0)+lgkmcnt(0) drained: tiles resident

    bf16x8 af[MI], bfr[4];
#pragma unroll
    for (int i = 0; i < MI; i++)
      af[i] = *(const bf16x8*)(&As[(wm + i * 16 + lrow) * 32 + quad * 8]);
#pragma unroll
    for (int j = 0; j < 4; j++)
      bfr[j] = *(const bf16x8*)(&Bs[(wn + j * 16 + lrow) * 32 + quad * 8]);
#pragma unroll
    for (int i = 0; i < MI; i++)
#pragma unroll
      for (int j = 0; j < 4; j++)
        acc[i][j] =
            __builtin_amdgcn_mfma_f32_16x16x32_bf16(af[i], bfr[j], acc[i][j], 0, 0, 0);
  }

  // C/D layout: col = lane&15, row = quad*4 + reg  [m89-verified]
#pragma unroll
  for (int i = 0; i < MI; i++) {
#pragma unroll
    for (int j = 0; j < 4; j++) {
      const int col = n0 + wn + j * 16 + lrow;
      const float bv = LOGITS ? bias[col] : 0.0f;
#pragma unroll
      for (int r = 0; r < 4; r++) {
        const int row = m0 + wm + i * 16 + quad * 4 + r;
        if (row < M) {
          if (LOGITS) Cf[(size_t)row * N + col] = acc[i][j][r] + bv;
          else        Cb[(size_t)row * N + col] = (__bf16)acc[i][j][r];
        }
      }
    }
  }
}

// ---------------------------------------------------------------------------
// GRU gates from gh (M x 6144 bf16, [left 3H | right 3H], no biases).
// children interleaved: left -> 2j, right -> 2j+1.  grid = (M, 4), block 256.
// ---------------------------------------------------------------------------
__global__ __launch_bounds__(256) void gru_gate(
    const __bf16* __restrict__ gh, const float* __restrict__ bih_l,
    const float* __restrict__ bhh_l, const float* __restrict__ bih_r,
    const float* __restrict__ bhh_r, const __bf16* __restrict__ hin,
    __bf16* __restrict__ hout, int n) {
  const int row = blockIdx.x;
  const int col = blockIdx.y * 256 + threadIdx.x;
  const int b = row / n, j = row - b * n;
  const size_t g6 = (size_t)row * 6144;
  const float hv = (float)hin[(size_t)row * H_DIM + col];
  const size_t obase = (size_t)(b * 2 * n + 2 * j) * H_DIM;

  {  // left child
    float gr = (float)gh[g6 + col] + bhh_l[col];
    float gz = (float)gh[g6 + 1024 + col] + bhh_l[1024 + col];
    float gn = (float)gh[g6 + 2048 + col] + bhh_l[2048 + col];
    float r = 1.f / (1.f + __expf(-(bih_l[col] + gr)));
    float z = 1.f / (1.f + __expf(-(bih_l[1024 + col] + gz)));
    float nn = tanhf(bih_l[2048 + col] + r * gn);
    hout[obase + col] = (__bf16)((1.f - z) * nn + z * hv);
  }
  {  // right child
    float gr = (float)gh[g6 + 3072 + col] + bhh_r[col];
    float gz = (float)gh[g6 + 4096 + col] + bhh_r[1024 + col];
    float gn = (float)gh[g6 + 5120 + col] + bhh_r[2048 + col];
    float r = 1.f / (1.f + __expf(-(bih_r[col] + gr)));
    float z = 1.f / (1.f + __expf(-(bih_r[1024 + col] + gz)));
    float nn = tanhf(bih_r[2048 + col] + r * gn);
    hout[obase + H_DIM + col] = (__bf16)((1.f - z) * nn + z * hv);
  }
}

// ---------------------------------------------------------------------------
// Online log_softmax, V=32000 fp32, in place. 2 passes (was 3):
// pass 1 reads + online (max,sum); pass 2 read-modify-write. float4 throughout.
// ---------------------------------------------------------------------------
__global__ __launch_bounds__(256) void logsoftmax_rows(float* __restrict__ out) {
  const int row = blockIdx.x;
  float4* p4 = (float4*)(out + (size_t)row * V_DIM);  // 8000 vec4
  const int tid = threadIdx.x;

  float m = -3.0e38f, s = 0.f;
  for (int i = tid; i < 8000; i += 256) {
    float4 v = p4[i];
    float cm = fmaxf(fmaxf(v.x, v.y), fmaxf(v.z, v.w));
    if (cm > m) { s *= __expf(m - cm); m = cm; }
    s += __expf(v.x - m) + __expf(v.y - m) + __expf(v.z - m) + __expf(v.w - m);
  }
#pragma unroll
  for (int off = 32; off; off >>= 1) {
    float om = __shfl_xor(m, off, 64);
    float os = __shfl_xor(s, off, 64);
    float nm = fmaxf(m, om);
    s = s * __expf(m - nm) + os * __expf(om - nm);
    m = nm;
  }
  __shared__ float rm[4], rs[4];
  if ((tid & 63) == 0) { rm[tid >> 6] = m; rs[tid >> 6] = s; }
  __syncthreads();
  const float M4 = fmaxf(fmaxf(rm[0], rm[1]), fmaxf(rm[2], rm[3]));
  const float S4 = rs[0] * __expf(rm[0] - M4) + rs[1] * __expf(rm[1] - M4) +
                   rs[2] * __expf(rm[2] - M4) + rs[3] * __expf(rm[3] - M4);
  const float lg = M4 + __logf(S4);
  for (int i = tid; i < 8000; i += 256) {
    float4 v = p4[i];
    v.x -= lg; v.y -= lg; v.z -= lg; v.w -= lg;
    p4[i] = v;
  }
}

// ---------------------------------------------------------------------------
extern "C" void kernel_launch(void* const* d_in, const int* in_sizes, int n_in,
                              void* d_out, int out_size, void* d_ws,
                              size_t ws_size, hipStream_t stream) {
  const float* enc   = (const float*)d_in[0];
  const float* Whh_l = (const float*)d_in[1];
  const float* bih_l = (const float*)d_in[2];
  const float* bhh_l = (const float*)d_in[3];
  const float* Whh_r = (const float*)d_in[4];
  const float* bih_r = (const float*)d_in[5];
  const float* bhh_r = (const float*)d_in[6];
  const float* W_out = (const float*)d_in[7];
  const float* b_out = (const float*)d_in[8];
  float* out = (float*)d_out;

  // ws layout (bytes). Base layout totals 33,685,504 B == round-2's proven-
  // safe usage. WoutB (bf16 W_out, 65.5 MB) only if ws_size allows.
  char* ws = (char*)d_ws;
  __bf16* ghb    = (__bf16*)ws;                          // 1024*6144*2 = 12,582,912
  __bf16* buf0   = (__bf16*)(ws + 12582912);             // 4 MB
  __bf16* buf1   = (__bf16*)(ws + 16777216);             // 4 MB
  __bf16* WhhB_l = (__bf16*)(ws + 20971520);             // 6,291,456
  __bf16* WhhB_r = WhhB_l + 3145728;                     // 6,291,456
  __bf16* encB   = (__bf16*)(ws + 33554432);             // 131,072 -> end 33,685,504
  __bf16* WoutB  = (__bf16*)(ws + 33685504);             // 65,536,000
  const bool big = ws_size >= (size_t)(33685504 + 65536000);

  f2b<<<256, 256, 0, stream>>>(Whh_l, WhhB_l, 3 * H_DIM * H_DIM);
  f2b<<<256, 256, 0, stream>>>(Whh_r, WhhB_r, 3 * H_DIM * H_DIM);
  f2b<<<64, 256, 0, stream>>>(enc, encB, B_DIM * H_DIM);
  if (big) f2b<<<1024, 256, 0, stream>>>(W_out, WoutB, V_DIM * H_DIM);

  const __bf16* cur = encB;
  __bf16* nxt = buf0;
  int n = 1;
  for (int d = 0; d < DEPTH_C; d++) {
    const int M = B_DIM * n;
    dim3 gg((M + 127) / 128, 6144 / 64);
    gemm_nt<64, false, true><<<gg, 256, 0, stream>>>(
        cur, WhhB_l, WhhB_r, nullptr, ghb, nullptr, nullptr, M, 6144);
    gru_gate<<<dim3(M, 4), 256, 0, stream>>>(ghb, bih_l, bhh_l, bih_r, bhh_r,
                                             cur, nxt, n);
    cur = nxt;
    nxt = (nxt == buf0) ? buf1 : buf0;
    n *= 2;
  }

  // logits = cur(2048x1024 bf16) @ W_out^T + b_out -> d_out fp32
  dim3 gf(2048 / 128, V_DIM / 128);
  if (big)
    gemm_nt<128, true, true><<<gf, 256, 0, stream>>>(
        cur, WoutB, nullptr, nullptr, nullptr, out, b_out, 2048, V_DIM);
  else
    gemm_nt<128, true, false><<<gf, 256, 0, stream>>>(
        cur, nullptr, nullptr, W_out, nullptr, out, b_out, 2048, V_DIM);
  logsoftmax_rows<<<2048, 256, 0, stream>>>(out);
}